// Round 6
// baseline (183.043 us; speedup 1.0000x reference)
//
#include <hip/hip_runtime.h>
#include <math.h>

// Sizes (fixed by the problem)
#define BATCH 512   // scan sequence length (original batch dim)
#define E     128
#define DI    256
#define S     256
#define DTR   8
#define KCONV 4
#define JWX   520   // dt(8) + B(256) + C(256)

__device__ __forceinline__ float silu_f(float v) {
    return v / (1.0f + __expf(-v));
}

// ---------------------------------------------------------------------------
// kA: heterogeneous fusion of weight transposes (blocks 512..538) and
//     conv2d+lin row-31 projection (blocks 0..511).
// ---------------------------------------------------------------------------
__global__ __launch_bounds__(256) void kA_pre(
    const float* __restrict__ x, const float* __restrict__ conv_w,
    const float* __restrict__ conv_b, const float* __restrict__ lin_w,
    const float* __restrict__ lin_b, float* __restrict__ u31,
    const float* __restrict__ W_in, const float* __restrict__ W_x,
    const float* __restrict__ W_dt, const float* __restrict__ W_out,
    const float* __restrict__ c1w,
    float* __restrict__ W_inT, float* __restrict__ W_xT,
    float* __restrict__ W_dtT, float* __restrict__ W_outT,
    float* __restrict__ c1wT)
{
    const int tid = threadIdx.x;
    if (blockIdx.x >= 512) {
        // ---- transpose part ----
        const int bid = blockIdx.x - 512;
        const float* src; float* dst; int J, K, j0;
        if (bid < 9)       { src = W_x;   dst = W_xT;   J = JWX; K = DI;    j0 = bid * 64; }
        else if (bid < 17) { src = W_in;  dst = W_inT;  J = 512; K = E;     j0 = (bid - 9) * 64; }
        else if (bid < 19) { src = W_out; dst = W_outT; J = E;   K = DI;    j0 = (bid - 17) * 64; }
        else if (bid < 23) { src = W_dt;  dst = W_dtT;  J = DI;  K = DTR;   j0 = (bid - 19) * 64; }
        else               { src = c1w;   dst = c1wT;   J = DI;  K = KCONV; j0 = (bid - 23) * 64; }
        const int j = j0 + (tid & 63);
        if (j >= J) return;
        for (int c = tid >> 6; c < K; c += 4)
            dst[c * J + j] = src[j * K + c];
        return;
    }

    // ---- conv2d + lin row 31 part ----
    const int b = blockIdx.x;
    __shared__ float lw[1024];
    __shared__ float red[10][4];
    __shared__ float Tsh[10];

    const float4 lv = ((const float4*)(lin_w + 31 * 1024))[tid];
    ((float4*)lw)[tid] = lv;
    __syncthreads();

    float acc[10];
#pragma unroll
    for (int k = 0; k < 10; k++) acc[k] = 0.0f;

    const float4 xv = ((const float4*)(x + (size_t)b * 1024))[tid];
    const int p0 = tid * 4;
    const int h = p0 >> 5, w0 = p0 & 31;
    const float xa[4] = {xv.x, xv.y, xv.z, xv.w};
#pragma unroll
    for (int k = 0; k < 4; k++) {
        const float xval = xa[k];
        const int w = w0 + k;
#pragma unroll
        for (int i = 0; i < 3; i++) {
            const int hh = h - (i - 1);
            if (hh < 0 || hh > 31) continue;
#pragma unroll
            for (int j = 0; j < 3; j++) {
                const int ww = w - (j - 1);
                if (ww < 0 || ww > 31) continue;
                acc[i * 3 + j] += xval * lw[hh * 32 + ww];
            }
        }
    }
    acc[9] = lv.x + lv.y + lv.z + lv.w;   // partial sum of lin_w row (SL)

    const int wv = tid >> 6, ln = tid & 63;
#pragma unroll
    for (int k = 0; k < 10; k++) {
#pragma unroll
        for (int m = 1; m < 64; m <<= 1) acc[k] += __shfl_xor(acc[k], m, 64);
    }
    if (ln == 0) {
#pragma unroll
        for (int k = 0; k < 10; k++) red[k][wv] = acc[k];
    }
    __syncthreads();
    if (tid < 10) Tsh[tid] = red[tid][0] + red[tid][1] + red[tid][2] + red[tid][3];
    __syncthreads();

    if (tid < E) {
        const int e = tid;
        float v = lin_b[31] + conv_b[e] * Tsh[9];
#pragma unroll
        for (int k = 0; k < 9; k++) v += conv_w[e * 9 + k] * Tsh[k];
        u31[b * E + e] = v;
    }
}

// ---------------------------------------------------------------------------
// K2a: xz[b,j] = sum_e u31[b,e]*W_inT[e,j]. Tile 4b x 64j, 1 output/thread.
// grid (128, 8) = 1024 blocks. Wave = one b-row, lanes on consecutive j.
// ---------------------------------------------------------------------------
__global__ __launch_bounds__(256) void k2a_win(
    const float* __restrict__ u31, const float* __restrict__ W_inT,
    float* __restrict__ xm, float* __restrict__ zg)
{
    const int bb = blockIdx.x * 4;
    const int tid = threadIdx.x;
    __shared__ float u[4][E];
    for (int i = tid; i < 4 * E; i += 256) u[i >> 7][i & 127] = u31[bb * E + i];
    __syncthreads();

    const int r = tid >> 6;
    const int j = blockIdx.y * 64 + (tid & 63);
    float a = 0.0f;
#pragma unroll 8
    for (int e = 0; e < E; e++) a += u[r][e] * W_inT[e * 512 + j];
    if (j < 256) xm[(bb + r) * DI + j] = a;
    else         zg[(bb + r) * DI + (j - 256)] = a;
}

// ---------------------------------------------------------------------------
// K2b: causal depthwise conv1d(K=4)+silu -> xs; dbl = xs @ W_x.T (via W_xT);
//      delta = softplus(dbl[:, :8] @ W_dt.T + b_dt); Bm/Cm split.
// Tile 4b x 64j, grid (128, 9). jgroup 0 also does xs_g write + delta.
// ---------------------------------------------------------------------------
__global__ __launch_bounds__(256) void k2b_conv_wx(
    const float* __restrict__ xm, const float* __restrict__ c1wT,
    const float* __restrict__ conv1d_b, const float* __restrict__ W_xT,
    const float* __restrict__ W_dtT, const float* __restrict__ b_dt,
    float* __restrict__ xs_g, float* __restrict__ delta_g,
    float* __restrict__ Bm, float* __restrict__ Cm)
{
    const int bb = blockIdx.x * 4;
    const int g = blockIdx.y;
    const int tid = threadIdx.x;
    __shared__ float xs[4][DI];
    __shared__ float dtin[4][8];

    // phase A: xs = silu(causal_conv1d(xm) + bias); coalesced
    for (int idx = tid; idx < 4 * DI; idx += 256) {
        const int r = idx >> 8, c = idx & 255;
        const int b = bb + r;
        float a = 0.0f;
#pragma unroll
        for (int k = 0; k < KCONV; k++) {
            const int src = b - 3 + k;
            if (src >= 0) a += xm[src * DI + c] * c1wT[k * DI + c];
        }
        a += conv1d_b[c];
        const float s = silu_f(a);
        xs[r][c] = s;
        if (g == 0) xs_g[b * DI + c] = s;
    }
    __syncthreads();

    // phase B: 1 output/thread; wave-uniform xs broadcast, coalesced W_xT
    const int r = tid >> 6;
    const int j = g * 64 + (tid & 63);
    if (j < JWX) {
        float a = 0.0f;
#pragma unroll 8
        for (int c = 0; c < DI; c++) a += xs[r][c] * W_xT[c * JWX + j];
        const int b = bb + r;
        if (j < DTR)          dtin[r][j] = a;
        else if (j < DTR + S) Bm[b * S + (j - DTR)] = a;
        else                  Cm[b * S + (j - DTR - S)] = a;
    }
    __syncthreads();

    // phase C: delta = softplus(dtin @ W_dt.T + b_dt) (jgroup 0 only)
    if (g == 0) {
        const int d = tid;
        const float bd = b_dt[d];
#pragma unroll
        for (int r2 = 0; r2 < 4; r2++) {
            float a = bd;
#pragma unroll
            for (int q = 0; q < DTR; q++) a += dtin[r2][q] * W_dtT[q * DI + d];
            const float sp = (a > 20.0f) ? a : log1pf(__expf(a));
            delta_g[(bb + r2) * DI + d] = sp;
        }
    }
}

// ---------------------------------------------------------------------------
// Value-splitting 8-value x 64-lane reduction.
// Input: pr[0..7] per lane. Output: every lane holds the full 64-lane sum of
// value index v = 4*(ln&1) + 2*((ln>>1)&1) + ((ln>>2)&1)  (bit-reversed ln&7).
// Cost: 10 shfl + 10 add + 14 select (vs 48 shfl + 48 add naive).
// ---------------------------------------------------------------------------
__device__ __forceinline__ float reduce8x64(const float pr[8], int ln) {
    const int b0 = ln & 1, b1 = (ln >> 1) & 1, b2 = (ln >> 2) & 1;
    float q[4];
#pragma unroll
    for (int i = 0; i < 4; i++) {
        const float mine  = b0 ? pr[i + 4] : pr[i];
        const float other = b0 ? pr[i]     : pr[i + 4];
        q[i] = mine + __shfl_xor(other, 1, 64);
    }
    float r2[2];
#pragma unroll
    for (int i = 0; i < 2; i++) {
        const float mine  = b1 ? q[i + 2] : q[i];
        const float other = b1 ? q[i]     : q[i + 2];
        r2[i] = mine + __shfl_xor(other, 2, 64);
    }
    const float mine  = b2 ? r2[1] : r2[0];
    const float other = b2 ? r2[0] : r2[1];
    float v = mine + __shfl_xor(other, 4, 64);
    v += __shfl_xor(v, 8, 64);
    v += __shfl_xor(v, 16, 64);
    v += __shfl_xor(v, 32, 64);
    return v;
}

__device__ __forceinline__ int tperm8(int ln) {
    return 4 * (ln & 1) + 2 * ((ln >> 1) & 1) + ((ln >> 2) & 1);
}

// ---------------------------------------------------------------------------
// K3 chunked parallel scan.
//   k3a: per-chunk local scan (h_in = 0), writes y_local, hloc, Dchunk
//   k3c: per-(chunk,d) block recomputes its carry from hloc/Dchunk (Horner,
//        bit-identical to a serial carry pass), then adds the fixup to y.
// Wave-uniform scalars (delta, xs, Dchunk) are loaded through readfirstlane'd
// indices so they compile to s_load instead of per-lane vector loads.
// ---------------------------------------------------------------------------
template <int NCv>
__global__ __launch_bounds__(256) void k3a_local(
    const float* __restrict__ A_log, const float* __restrict__ delta,
    const float* __restrict__ xs, const float* __restrict__ Bm,
    const float* __restrict__ Cm, float* __restrict__ y,
    float* __restrict__ hloc, float* __restrict__ Dchunk)
{
    constexpr int TCv = BATCH / NCv;
    const int tid = threadIdx.x;
    const int wv = tid >> 6, ln = tid & 63;
    const int d = blockIdx.x * 4 + wv;
    const int s0 = ln * 4;
    const int c = blockIdx.y;
    const int t0 = c * TCv;

    const float4 al = *(const float4*)(A_log + d * S + s0);
    float4 A;
    A.x = -__expf(al.x); A.y = -__expf(al.y);
    A.z = -__expf(al.z); A.w = -__expf(al.w);

    float4 h = make_float4(0.f, 0.f, 0.f, 0.f);
    float cd = 0.0f;
    float pr[8];

    for (int tb = 0; tb < TCv; tb += 8) {
#pragma unroll
        for (int i = 0; i < 8; i++) {
            const int tt = t0 + tb + i;
            const int ui = __builtin_amdgcn_readfirstlane(tt * DI + d);
            const float dd = delta[ui];
            cd += dd;
            const float u = dd * xs[ui];
            const float4 B = *(const float4*)(Bm + tt * S + s0);
            const float4 C = *(const float4*)(Cm + tt * S + s0);
            h.x = __expf(dd * A.x) * h.x + u * B.x;
            h.y = __expf(dd * A.y) * h.y + u * B.y;
            h.z = __expf(dd * A.z) * h.z + u * B.z;
            h.w = __expf(dd * A.w) * h.w + u * B.w;
            pr[i] = h.x * C.x + h.y * C.y + h.z * C.z + h.w * C.w;
        }
        const float v = reduce8x64(pr, ln);
        if (ln < 8) y[(t0 + tb + tperm8(ln)) * DI + d] = v;
    }

    *(float4*)(hloc + ((size_t)(c * DI + d)) * S + s0) = h;
    if (ln == 0) Dchunk[c * DI + d] = cd;
}

template <int NCv>
__global__ __launch_bounds__(256) void k3c_fix(
    const float* __restrict__ A_log, const float* __restrict__ delta,
    const float* __restrict__ Cm, const float* __restrict__ hloc,
    const float* __restrict__ Dchunk, float* __restrict__ y)
{
    constexpr int TCv = BATCH / NCv;
    const int tid = threadIdx.x;
    const int wv = tid >> 6, ln = tid & 63;
    const int d = blockIdx.x * 4 + wv;
    const int c = blockIdx.y + 1;
    const int s0 = ln * 4;
    const int t0 = c * TCv;

    const float4 al = *(const float4*)(A_log + d * S + s0);
    float4 A;
    A.x = -__expf(al.x); A.y = -__expf(al.y);
    A.z = -__expf(al.z); A.w = -__expf(al.w);

    // carry: hin[c] via the serial recurrence h = hloc[cp-1] + exp(A*D[cp-1])*h
    float4 hi = make_float4(0.f, 0.f, 0.f, 0.f);
    for (int cp = 1; cp <= c; cp++) {
        const float4 hl = *(const float4*)(hloc + ((size_t)((cp - 1) * DI + d)) * S + s0);
        const int di = __builtin_amdgcn_readfirstlane((cp - 1) * DI + d);
        const float Dc = Dchunk[di];
        hi.x = hl.x + __expf(A.x * Dc) * hi.x;
        hi.y = hl.y + __expf(A.y * Dc) * hi.y;
        hi.z = hl.z + __expf(A.z * Dc) * hi.z;
        hi.w = hl.w + __expf(A.w * Dc) * hi.w;
    }

    float cd = 0.0f;
    float pr[8];

    for (int tb = 0; tb < TCv; tb += 8) {
#pragma unroll
        for (int i = 0; i < 8; i++) {
            const int tt = t0 + tb + i;
            const int ui = __builtin_amdgcn_readfirstlane(tt * DI + d);
            const float dd = delta[ui];
            cd += dd;
            const float4 C = *(const float4*)(Cm + tt * S + s0);
            const float fx = hi.x * __expf(cd * A.x);
            const float fy = hi.y * __expf(cd * A.y);
            const float fz = hi.z * __expf(cd * A.z);
            const float fw = hi.w * __expf(cd * A.w);
            pr[i] = fx * C.x + fy * C.y + fz * C.z + fw * C.w;
        }
        const float v = reduce8x64(pr, ln);
        if (ln < 8) {
            const int tt = t0 + tb + tperm8(ln);
            y[tt * DI + d] += v;
        }
    }
}

// ---------------------------------------------------------------------------
// K4: yf = (y + xs*Dp)*silu(zg); feat = yf @ W_outT; 3 head matmuls -> d_out
// ---------------------------------------------------------------------------
__global__ __launch_bounds__(256) void k4_heads(
    const float* __restrict__ y, const float* __restrict__ xs,
    const float* __restrict__ Dp, const float* __restrict__ zg,
    const float* __restrict__ W_outT,
    const float* __restrict__ We, const float* __restrict__ be,
    const float* __restrict__ Wa, const float* __restrict__ ba,
    const float* __restrict__ Wq, const float* __restrict__ bq,
    float* __restrict__ out)
{
    const int bb = blockIdx.x * 2;
    const int tid = threadIdx.x;
    __shared__ float yf[2][DI];
    __shared__ float feat[2][E];

    for (int idx = tid; idx < 2 * DI; idx += 256) {
        const int r = idx >> 8, c = idx & 255;
        const int b = bb + r;
        const float z = zg[b * DI + c];
        yf[r][c] = (y[b * DI + c] + xs[b * DI + c] * Dp[c]) * silu_f(z);
    }
    __syncthreads();

    {
        const int r = tid >> 7, e = tid & 127;
        float a = 0.0f;
#pragma unroll 8
        for (int dd = 0; dd < DI; dd++) a += yf[r][dd] * W_outT[dd * E + e];
        feat[r][e] = a;
    }
    __syncthreads();

    if (tid < 16) {
        const int r = tid >> 3, hd = tid & 7;
        const int b = bb + r;
        const float* wrow;
        float bias;
        int dst;
        if (hd == 0)      { wrow = We;                 bias = be[0];      dst = b; }
        else if (hd < 4)  { wrow = Wa + (hd - 1) * E;  bias = ba[hd - 1]; dst = 512 + b * 3 + (hd - 1); }
        else              { wrow = Wq + (hd - 4) * E;  bias = bq[hd - 4]; dst = 2048 + b * 4 + (hd - 4); }
        float a = bias;
#pragma unroll 4
        for (int e = 0; e < E; e++) a += feat[r][e] * wrow[e];
        out[dst] = a;
    }
}

// ---------------------------------------------------------------------------
template <int NCv>
static void launch_scan(const float* A_log, const float* delta, const float* xs,
                        const float* Bm, const float* Cm, float* y,
                        float* hloc, float* Dchunk, hipStream_t stream)
{
    k3a_local<NCv><<<dim3(64, NCv), 256, 0, stream>>>(A_log, delta, xs, Bm, Cm, y, hloc, Dchunk);
    k3c_fix<NCv><<<dim3(64, NCv - 1), 256, 0, stream>>>(A_log, delta, Cm, hloc, Dchunk, y);
}

extern "C" void kernel_launch(void* const* d_in, const int* in_sizes, int n_in,
                              void* d_out, int out_size, void* d_ws, size_t ws_size,
                              hipStream_t stream)
{
    const float* x        = (const float*)d_in[0];
    const float* conv_w   = (const float*)d_in[1];
    const float* conv_b   = (const float*)d_in[2];
    const float* lin_w    = (const float*)d_in[3];
    const float* lin_b    = (const float*)d_in[4];
    const float* W_in     = (const float*)d_in[5];
    const float* conv1d_w = (const float*)d_in[6];
    const float* conv1d_b = (const float*)d_in[7];
    const float* W_x      = (const float*)d_in[8];
    const float* W_dt     = (const float*)d_in[9];
    const float* b_dt     = (const float*)d_in[10];
    const float* A_log    = (const float*)d_in[11];
    const float* Dp       = (const float*)d_in[12];
    const float* W_out    = (const float*)d_in[13];
    const float* We       = (const float*)d_in[14];
    const float* be       = (const float*)d_in[15];
    const float* Wa       = (const float*)d_in[16];
    const float* ba       = (const float*)d_in[17];
    const float* Wq       = (const float*)d_in[18];
    const float* bq       = (const float*)d_in[19];
    float* out = (float*)d_out;

    float* ws = (float*)d_ws;
    float* u31    = ws;                    // 512*128
    float* xm     = u31    + 512 * 128;    // 512*256 each below
    float* zg     = xm     + 512 * 256;
    float* xs     = zg     + 512 * 256;
    float* delta  = xs     + 512 * 256;
    float* Bm     = delta  + 512 * 256;
    float* Cm     = Bm     + 512 * 256;
    float* y      = Cm     + 512 * 256;
    float* W_inT  = y      + 512 * 256;    // 128*512
    float* W_xT   = W_inT  + 128 * 512;    // 256*520
    float* W_dtT  = W_xT   + 256 * JWX;    // 8*256
    float* W_outT = W_dtT  + 8 * 256;      // 256*128
    float* c1wT   = W_outT + 256 * 128;    // 4*256
    float* tail   = c1wT   + 4 * 256;      // hloc / Dchunk

    const size_t base_floats = (size_t)(tail - ws);
    const size_t avail = ws_size / 4 - base_floats;

    kA_pre<<<539, 256, 0, stream>>>(x, conv_w, conv_b, lin_w, lin_b, u31,
                                    W_in, W_x, W_dt, W_out, conv1d_w,
                                    W_inT, W_xT, W_dtT, W_outT, c1wT);
    k2a_win<<<dim3(128, 8), 256, 0, stream>>>(u31, W_inT, xm, zg);
    k2b_conv_wx<<<dim3(128, 9), 256, 0, stream>>>(xm, c1wT, conv1d_b, W_xT, W_dtT, b_dt,
                                                  xs, delta, Bm, Cm);

    // need: NC*DI*S + NC*DI floats for hloc + Dchunk
    if (avail >= (size_t)32 * DI * S + 32 * DI) {
        float* hloc = tail;
        float* Dch  = hloc + (size_t)32 * DI * S;
        launch_scan<32>(A_log, delta, xs, Bm, Cm, y, hloc, Dch, stream);
    } else if (avail >= (size_t)16 * DI * S + 16 * DI) {
        float* hloc = tail;
        float* Dch  = hloc + (size_t)16 * DI * S;
        launch_scan<16>(A_log, delta, xs, Bm, Cm, y, hloc, Dch, stream);
    } else {
        float* hloc = tail;
        float* Dch  = hloc + (size_t)8 * DI * S;
        launch_scan<8>(A_log, delta, xs, Bm, Cm, y, hloc, Dch, stream);
    }

    k4_heads<<<256, 256, 0, stream>>>(y, xs, Dp, zg, W_outT, We, be, Wa, ba, Wq, bq, out);
}

// Round 7
// 181.887 us; speedup vs baseline: 1.0064x; 1.0064x over previous
//
#include <hip/hip_runtime.h>
#include <math.h>

// Sizes (fixed by the problem)
#define BATCH 512   // scan sequence length (original batch dim)
#define E     128
#define DI    256
#define S     256
#define DTR   8
#define KCONV 4
#define JWX   520   // dt(8) + B(256) + C(256)

__device__ __forceinline__ float silu_f(float v) {
    return v / (1.0f + __expf(-v));
}

// ---------------------------------------------------------------------------
// kA: heterogeneous fusion of weight transposes (blocks 512..538) and
//     conv2d+lin row-31 projection (blocks 0..511).
// ---------------------------------------------------------------------------
__global__ __launch_bounds__(256) void kA_pre(
    const float* __restrict__ x, const float* __restrict__ conv_w,
    const float* __restrict__ conv_b, const float* __restrict__ lin_w,
    const float* __restrict__ lin_b, float* __restrict__ u31,
    const float* __restrict__ W_in, const float* __restrict__ W_x,
    const float* __restrict__ W_dt, const float* __restrict__ W_out,
    const float* __restrict__ c1w,
    float* __restrict__ W_inT, float* __restrict__ W_xT,
    float* __restrict__ W_dtT, float* __restrict__ W_outT,
    float* __restrict__ c1wT)
{
    const int tid = threadIdx.x;
    if (blockIdx.x >= 512) {
        // ---- transpose part ----
        const int bid = blockIdx.x - 512;
        const float* src; float* dst; int J, K, j0;
        if (bid < 9)       { src = W_x;   dst = W_xT;   J = JWX; K = DI;    j0 = bid * 64; }
        else if (bid < 17) { src = W_in;  dst = W_inT;  J = 512; K = E;     j0 = (bid - 9) * 64; }
        else if (bid < 19) { src = W_out; dst = W_outT; J = E;   K = DI;    j0 = (bid - 17) * 64; }
        else if (bid < 23) { src = W_dt;  dst = W_dtT;  J = DI;  K = DTR;   j0 = (bid - 19) * 64; }
        else               { src = c1w;   dst = c1wT;   J = DI;  K = KCONV; j0 = (bid - 23) * 64; }
        const int j = j0 + (tid & 63);
        if (j >= J) return;
        for (int c = tid >> 6; c < K; c += 4)
            dst[c * J + j] = src[j * K + c];
        return;
    }

    // ---- conv2d + lin row 31 part ----
    const int b = blockIdx.x;
    __shared__ float lw[1024];
    __shared__ float red[10][4];
    __shared__ float Tsh[10];

    const float4 lv = ((const float4*)(lin_w + 31 * 1024))[tid];
    ((float4*)lw)[tid] = lv;
    __syncthreads();

    float acc[10];
#pragma unroll
    for (int k = 0; k < 10; k++) acc[k] = 0.0f;

    const float4 xv = ((const float4*)(x + (size_t)b * 1024))[tid];
    const int p0 = tid * 4;
    const int h = p0 >> 5, w0 = p0 & 31;
    const float xa[4] = {xv.x, xv.y, xv.z, xv.w};
#pragma unroll
    for (int k = 0; k < 4; k++) {
        const float xval = xa[k];
        const int w = w0 + k;
#pragma unroll
        for (int i = 0; i < 3; i++) {
            const int hh = h - (i - 1);
            if (hh < 0 || hh > 31) continue;
#pragma unroll
            for (int j = 0; j < 3; j++) {
                const int ww = w - (j - 1);
                if (ww < 0 || ww > 31) continue;
                acc[i * 3 + j] += xval * lw[hh * 32 + ww];
            }
        }
    }
    acc[9] = lv.x + lv.y + lv.z + lv.w;   // partial sum of lin_w row (SL)

    const int wv = tid >> 6, ln = tid & 63;
#pragma unroll
    for (int k = 0; k < 10; k++) {
#pragma unroll
        for (int m = 1; m < 64; m <<= 1) acc[k] += __shfl_xor(acc[k], m, 64);
    }
    if (ln == 0) {
#pragma unroll
        for (int k = 0; k < 10; k++) red[k][wv] = acc[k];
    }
    __syncthreads();
    if (tid < 10) Tsh[tid] = red[tid][0] + red[tid][1] + red[tid][2] + red[tid][3];
    __syncthreads();

    if (tid < E) {
        const int e = tid;
        float v = lin_b[31] + conv_b[e] * Tsh[9];
#pragma unroll
        for (int k = 0; k < 9; k++) v += conv_w[e * 9 + k] * Tsh[k];
        u31[b * E + e] = v;
    }
}

// ---------------------------------------------------------------------------
// K2a: xz[b,j] = sum_e u31[b,e]*W_inT[e,j]. Tile 4b x 64j, 1 output/thread.
// grid (128, 8) = 1024 blocks. Wave = one b-row, lanes on consecutive j.
// ---------------------------------------------------------------------------
__global__ __launch_bounds__(256) void k2a_win(
    const float* __restrict__ u31, const float* __restrict__ W_inT,
    float* __restrict__ xm, float* __restrict__ zg)
{
    const int bb = blockIdx.x * 4;
    const int tid = threadIdx.x;
    __shared__ float u[4][E];
    for (int i = tid; i < 4 * E; i += 256) u[i >> 7][i & 127] = u31[bb * E + i];
    __syncthreads();

    const int r = tid >> 6;
    const int j = blockIdx.y * 64 + (tid & 63);
    float a = 0.0f;
#pragma unroll 8
    for (int e = 0; e < E; e++) a += u[r][e] * W_inT[e * 512 + j];
    if (j < 256) xm[(bb + r) * DI + j] = a;
    else         zg[(bb + r) * DI + (j - 256)] = a;
}

// ---------------------------------------------------------------------------
// K2b: causal depthwise conv1d(K=4)+silu -> xs; dbl = xs @ W_x.T (via W_xT);
//      delta = softplus(dbl[:, :8] @ W_dt.T + b_dt); Bm/Cm split.
// Tile 4b x 64j, grid (128, 9). jgroup 0 also does xs_g write + delta.
// ---------------------------------------------------------------------------
__global__ __launch_bounds__(256) void k2b_conv_wx(
    const float* __restrict__ xm, const float* __restrict__ c1wT,
    const float* __restrict__ conv1d_b, const float* __restrict__ W_xT,
    const float* __restrict__ W_dtT, const float* __restrict__ b_dt,
    float* __restrict__ xs_g, float* __restrict__ delta_g,
    float* __restrict__ Bm, float* __restrict__ Cm)
{
    const int bb = blockIdx.x * 4;
    const int g = blockIdx.y;
    const int tid = threadIdx.x;
    __shared__ float xs[4][DI];
    __shared__ float dtin[4][8];

    // phase A: xs = silu(causal_conv1d(xm) + bias); coalesced
    for (int idx = tid; idx < 4 * DI; idx += 256) {
        const int r = idx >> 8, c = idx & 255;
        const int b = bb + r;
        float a = 0.0f;
#pragma unroll
        for (int k = 0; k < KCONV; k++) {
            const int src = b - 3 + k;
            if (src >= 0) a += xm[src * DI + c] * c1wT[k * DI + c];
        }
        a += conv1d_b[c];
        const float s = silu_f(a);
        xs[r][c] = s;
        if (g == 0) xs_g[b * DI + c] = s;
    }
    __syncthreads();

    // phase B: 1 output/thread; wave-uniform xs broadcast, coalesced W_xT
    const int r = tid >> 6;
    const int j = g * 64 + (tid & 63);
    if (j < JWX) {
        float a = 0.0f;
#pragma unroll 8
        for (int c = 0; c < DI; c++) a += xs[r][c] * W_xT[c * JWX + j];
        const int b = bb + r;
        if (j < DTR)          dtin[r][j] = a;
        else if (j < DTR + S) Bm[b * S + (j - DTR)] = a;
        else                  Cm[b * S + (j - DTR - S)] = a;
    }
    __syncthreads();

    // phase C: delta = softplus(dtin @ W_dt.T + b_dt) (jgroup 0 only)
    if (g == 0) {
        const int d = tid;
        const float bd = b_dt[d];
#pragma unroll
        for (int r2 = 0; r2 < 4; r2++) {
            float a = bd;
#pragma unroll
            for (int q = 0; q < DTR; q++) a += dtin[r2][q] * W_dtT[q * DI + d];
            const float sp = (a > 20.0f) ? a : log1pf(__expf(a));
            delta_g[(bb + r2) * DI + d] = sp;
        }
    }
}

// ---------------------------------------------------------------------------
// Value-splitting 8-value x 64-lane reduction.
// Output: every lane holds the 64-lane sum of value index tperm8(ln&7).
// ---------------------------------------------------------------------------
__device__ __forceinline__ float reduce8x64(const float pr[8], int ln) {
    const int b0 = ln & 1, b1 = (ln >> 1) & 1, b2 = (ln >> 2) & 1;
    float q[4];
#pragma unroll
    for (int i = 0; i < 4; i++) {
        const float mine  = b0 ? pr[i + 4] : pr[i];
        const float other = b0 ? pr[i]     : pr[i + 4];
        q[i] = mine + __shfl_xor(other, 1, 64);
    }
    float r2[2];
#pragma unroll
    for (int i = 0; i < 2; i++) {
        const float mine  = b1 ? q[i + 2] : q[i];
        const float other = b1 ? q[i]     : q[i + 2];
        r2[i] = mine + __shfl_xor(other, 2, 64);
    }
    const float mine  = b2 ? r2[1] : r2[0];
    const float other = b2 ? r2[0] : r2[1];
    float v = mine + __shfl_xor(other, 4, 64);
    v += __shfl_xor(v, 8, 64);
    v += __shfl_xor(v, 16, 64);
    v += __shfl_xor(v, 32, 64);
    return v;
}

__device__ __forceinline__ int tperm8(int ln) {
    return 4 * (ln & 1) + 2 * ((ln >> 1) & 1) + ((ln >> 2) & 1);
}

// ---------------------------------------------------------------------------
// K3 chunked parallel scan, 4 d's per wave (Bm/Cm float4 loads amortized 4x).
//   k3a: per-chunk local scan (h_in = 0), writes y_local, hloc, Dchunk
//   k3c: recomputes carry from hloc/Dchunk (Horner, order-identical), fixup y.
// grid k3a: (16, NC); block = 4 waves; wave wv owns d0 = bx*16 + wv*4 .. +3.
// ---------------------------------------------------------------------------
template <int NCv>
__global__ __launch_bounds__(256) void k3a_local(
    const float* __restrict__ A_log, const float* __restrict__ delta,
    const float* __restrict__ xs, const float* __restrict__ Bm,
    const float* __restrict__ Cm, float* __restrict__ y,
    float* __restrict__ hloc, float* __restrict__ Dchunk)
{
    constexpr int TCv = BATCH / NCv;
    const int tid = threadIdx.x;
    const int wv = tid >> 6, ln = tid & 63;
    const int d0 = blockIdx.x * 16 + wv * 4;
    const int s0 = ln * 4;
    const int c = blockIdx.y;
    const int t0 = c * TCv;

    float4 A[4], h[4];
    float cd[4];
#pragma unroll
    for (int r = 0; r < 4; r++) {
        const float4 al = *(const float4*)(A_log + (d0 + r) * S + s0);
        A[r].x = -__expf(al.x); A[r].y = -__expf(al.y);
        A[r].z = -__expf(al.z); A[r].w = -__expf(al.w);
        h[r] = make_float4(0.f, 0.f, 0.f, 0.f);
        cd[r] = 0.0f;
    }

    float pr[4][8];

    for (int tb = 0; tb < TCv; tb += 8) {
#pragma unroll
        for (int i = 0; i < 8; i++) {
            const int tt = t0 + tb + i;
            const float4 B = *(const float4*)(Bm + tt * S + s0);
            const float4 C = *(const float4*)(Cm + tt * S + s0);
#pragma unroll
            for (int r = 0; r < 4; r++) {
                const int ui = __builtin_amdgcn_readfirstlane(tt * DI + d0 + r);
                const float dd = delta[ui];
                cd[r] += dd;
                const float u = dd * xs[ui];
                h[r].x = __expf(dd * A[r].x) * h[r].x + u * B.x;
                h[r].y = __expf(dd * A[r].y) * h[r].y + u * B.y;
                h[r].z = __expf(dd * A[r].z) * h[r].z + u * B.z;
                h[r].w = __expf(dd * A[r].w) * h[r].w + u * B.w;
                pr[r][i] = h[r].x * C.x + h[r].y * C.y + h[r].z * C.z + h[r].w * C.w;
            }
        }
#pragma unroll
        for (int r = 0; r < 4; r++) {
            const float v = reduce8x64(pr[r], ln);
            if (ln < 8) y[(t0 + tb + tperm8(ln)) * DI + d0 + r] = v;
        }
    }

#pragma unroll
    for (int r = 0; r < 4; r++)
        *(float4*)(hloc + ((size_t)(c * DI + d0 + r)) * S + s0) = h[r];
    if (ln == 0) {
#pragma unroll
        for (int r = 0; r < 4; r++) Dchunk[c * DI + d0 + r] = cd[r];
    }
}

template <int NCv>
__global__ __launch_bounds__(256) void k3c_fix(
    const float* __restrict__ A_log, const float* __restrict__ delta,
    const float* __restrict__ Cm, const float* __restrict__ hloc,
    const float* __restrict__ Dchunk, float* __restrict__ y)
{
    constexpr int TCv = BATCH / NCv;
    const int tid = threadIdx.x;
    const int wv = tid >> 6, ln = tid & 63;
    const int d0 = blockIdx.x * 16 + wv * 4;
    const int c = blockIdx.y + 1;
    const int s0 = ln * 4;
    const int t0 = c * TCv;

    float4 A[4], hi[4];
    float cd[4];
#pragma unroll
    for (int r = 0; r < 4; r++) {
        const float4 al = *(const float4*)(A_log + (d0 + r) * S + s0);
        A[r].x = -__expf(al.x); A[r].y = -__expf(al.y);
        A[r].z = -__expf(al.z); A[r].w = -__expf(al.w);
        hi[r] = make_float4(0.f, 0.f, 0.f, 0.f);
        cd[r] = 0.0f;
    }

    // carry: hin[c] via the serial recurrence h = hloc[cp-1] + exp(A*D[cp-1])*h
    for (int cp = 1; cp <= c; cp++) {
#pragma unroll
        for (int r = 0; r < 4; r++) {
            const float4 hl = *(const float4*)(hloc + ((size_t)((cp - 1) * DI + d0 + r)) * S + s0);
            const int di = __builtin_amdgcn_readfirstlane((cp - 1) * DI + d0 + r);
            const float Dc = Dchunk[di];
            hi[r].x = hl.x + __expf(A[r].x * Dc) * hi[r].x;
            hi[r].y = hl.y + __expf(A[r].y * Dc) * hi[r].y;
            hi[r].z = hl.z + __expf(A[r].z * Dc) * hi[r].z;
            hi[r].w = hl.w + __expf(A[r].w * Dc) * hi[r].w;
        }
    }

    float pr[4][8];

    for (int tb = 0; tb < TCv; tb += 8) {
#pragma unroll
        for (int i = 0; i < 8; i++) {
            const int tt = t0 + tb + i;
            const float4 C = *(const float4*)(Cm + tt * S + s0);
#pragma unroll
            for (int r = 0; r < 4; r++) {
                const int ui = __builtin_amdgcn_readfirstlane(tt * DI + d0 + r);
                const float dd = delta[ui];
                cd[r] += dd;
                const float fx = hi[r].x * __expf(cd[r] * A[r].x);
                const float fy = hi[r].y * __expf(cd[r] * A[r].y);
                const float fz = hi[r].z * __expf(cd[r] * A[r].z);
                const float fw = hi[r].w * __expf(cd[r] * A[r].w);
                pr[r][i] = fx * C.x + fy * C.y + fz * C.z + fw * C.w;
            }
        }
#pragma unroll
        for (int r = 0; r < 4; r++) {
            const float v = reduce8x64(pr[r], ln);
            if (ln < 8) {
                const int tt = t0 + tb + tperm8(ln);
                y[tt * DI + d0 + r] += v;
            }
        }
    }
}

// ---------------------------------------------------------------------------
// K4: yf = (y + xs*Dp)*silu(zg); feat = yf @ W_outT; 3 head matmuls -> d_out
// ---------------------------------------------------------------------------
__global__ __launch_bounds__(256) void k4_heads(
    const float* __restrict__ y, const float* __restrict__ xs,
    const float* __restrict__ Dp, const float* __restrict__ zg,
    const float* __restrict__ W_outT,
    const float* __restrict__ We, const float* __restrict__ be,
    const float* __restrict__ Wa, const float* __restrict__ ba,
    const float* __restrict__ Wq, const float* __restrict__ bq,
    float* __restrict__ out)
{
    const int bb = blockIdx.x * 2;
    const int tid = threadIdx.x;
    __shared__ float yf[2][DI];
    __shared__ float feat[2][E];

    for (int idx = tid; idx < 2 * DI; idx += 256) {
        const int r = idx >> 8, c = idx & 255;
        const int b = bb + r;
        const float z = zg[b * DI + c];
        yf[r][c] = (y[b * DI + c] + xs[b * DI + c] * Dp[c]) * silu_f(z);
    }
    __syncthreads();

    {
        const int r = tid >> 7, e = tid & 127;
        float a = 0.0f;
#pragma unroll 8
        for (int dd = 0; dd < DI; dd++) a += yf[r][dd] * W_outT[dd * E + e];
        feat[r][e] = a;
    }
    __syncthreads();

    if (tid < 16) {
        const int r = tid >> 3, hd = tid & 7;
        const int b = bb + r;
        const float* wrow;
        float bias;
        int dst;
        if (hd == 0)      { wrow = We;                 bias = be[0];      dst = b; }
        else if (hd < 4)  { wrow = Wa + (hd - 1) * E;  bias = ba[hd - 1]; dst = 512 + b * 3 + (hd - 1); }
        else              { wrow = Wq + (hd - 4) * E;  bias = bq[hd - 4]; dst = 2048 + b * 4 + (hd - 4); }
        float a = bias;
#pragma unroll 4
        for (int e = 0; e < E; e++) a += feat[r][e] * wrow[e];
        out[dst] = a;
    }
}

// ---------------------------------------------------------------------------
template <int NCv>
static void launch_scan(const float* A_log, const float* delta, const float* xs,
                        const float* Bm, const float* Cm, float* y,
                        float* hloc, float* Dchunk, hipStream_t stream)
{
    k3a_local<NCv><<<dim3(16, NCv), 256, 0, stream>>>(A_log, delta, xs, Bm, Cm, y, hloc, Dchunk);
    k3c_fix<NCv><<<dim3(16, NCv - 1), 256, 0, stream>>>(A_log, delta, Cm, hloc, Dchunk, y);
}

extern "C" void kernel_launch(void* const* d_in, const int* in_sizes, int n_in,
                              void* d_out, int out_size, void* d_ws, size_t ws_size,
                              hipStream_t stream)
{
    const float* x        = (const float*)d_in[0];
    const float* conv_w   = (const float*)d_in[1];
    const float* conv_b   = (const float*)d_in[2];
    const float* lin_w    = (const float*)d_in[3];
    const float* lin_b    = (const float*)d_in[4];
    const float* W_in     = (const float*)d_in[5];
    const float* conv1d_w = (const float*)d_in[6];
    const float* conv1d_b = (const float*)d_in[7];
    const float* W_x      = (const float*)d_in[8];
    const float* W_dt     = (const float*)d_in[9];
    const float* b_dt     = (const float*)d_in[10];
    const float* A_log    = (const float*)d_in[11];
    const float* Dp       = (const float*)d_in[12];
    const float* W_out    = (const float*)d_in[13];
    const float* We       = (const float*)d_in[14];
    const float* be       = (const float*)d_in[15];
    const float* Wa       = (const float*)d_in[16];
    const float* ba       = (const float*)d_in[17];
    const float* Wq       = (const float*)d_in[18];
    const float* bq       = (const float*)d_in[19];
    float* out = (float*)d_out;

    float* ws = (float*)d_ws;
    float* u31    = ws;                    // 512*128
    float* xm     = u31    + 512 * 128;    // 512*256 each below
    float* zg     = xm     + 512 * 256;
    float* xs     = zg     + 512 * 256;
    float* delta  = xs     + 512 * 256;
    float* Bm     = delta  + 512 * 256;
    float* Cm     = Bm     + 512 * 256;
    float* y      = Cm     + 512 * 256;
    float* W_inT  = y      + 512 * 256;    // 128*512
    float* W_xT   = W_inT  + 128 * 512;    // 256*520
    float* W_dtT  = W_xT   + 256 * JWX;    // 8*256
    float* W_outT = W_dtT  + 8 * 256;      // 256*128
    float* c1wT   = W_outT + 256 * 128;    // 4*256
    float* tail   = c1wT   + 4 * 256;      // hloc / Dchunk

    const size_t base_floats = (size_t)(tail - ws);
    const size_t avail = ws_size / 4 - base_floats;

    kA_pre<<<539, 256, 0, stream>>>(x, conv_w, conv_b, lin_w, lin_b, u31,
                                    W_in, W_x, W_dt, W_out, conv1d_w,
                                    W_inT, W_xT, W_dtT, W_outT, c1wT);
    k2a_win<<<dim3(128, 8), 256, 0, stream>>>(u31, W_inT, xm, zg);
    k2b_conv_wx<<<dim3(128, 9), 256, 0, stream>>>(xm, c1wT, conv1d_b, W_xT, W_dtT, b_dt,
                                                  xs, delta, Bm, Cm);

    // need: NC*DI*S + NC*DI floats for hloc + Dchunk
    if (avail >= (size_t)32 * DI * S + 32 * DI) {
        float* hloc = tail;
        float* Dch  = hloc + (size_t)32 * DI * S;
        launch_scan<32>(A_log, delta, xs, Bm, Cm, y, hloc, Dch, stream);
    } else if (avail >= (size_t)16 * DI * S + 16 * DI) {
        float* hloc = tail;
        float* Dch  = hloc + (size_t)16 * DI * S;
        launch_scan<16>(A_log, delta, xs, Bm, Cm, y, hloc, Dch, stream);
    } else {
        float* hloc = tail;
        float* Dch  = hloc + (size_t)8 * DI * S;
        launch_scan<8>(A_log, delta, xs, Bm, Cm, y, hloc, Dch, stream);
    }

    k4_heads<<<256, 256, 0, stream>>>(y, xs, Dp, zg, W_outT, We, be, Wa, ba, Wq, bq, out);
}